// Round 1
// baseline (719.739 us; speedup 1.0000x reference)
//
#include <hip/hip_runtime.h>

#define GRID   1024
#define BLOCK  256
#define BATCH  16384
#define NJ     25
#define DEPTH  256
#define ITERS  (BATCH / GRID)

typedef short s16x8 __attribute__((ext_vector_type(8)));
typedef short s16x4 __attribute__((ext_vector_type(4)));
typedef float f32x4 __attribute__((ext_vector_type(4)));

// fp32 -> bf16 with round-to-nearest-even (deterministic, header-independent)
__device__ __forceinline__ short f2bf(float f) {
  union { float f; unsigned u; } c; c.f = f;
  unsigned r = (c.u + 0x7FFFu + ((c.u >> 16) & 1u)) >> 16;
  return (short)r;
}

#define MFMA(a, b, c) __builtin_amdgcn_mfma_f32_16x16x32_bf16((a), (b), (c), 0, 0, 0)

__global__ __launch_bounds__(BLOCK, 2)
void geo_gcn_fused(const float* __restrict__ x,
                   const float* __restrict__ w,
                   float* __restrict__ out)
{
  // LDS: A chunk double-buffer (32 rows x 64 cols bf16, pitch 72 for bank spread),
  // P (32x32 bf16, pitch 40), s3 scratch fp32 (pitch 33), per-wave Y transpose scratch.
  __shared__ short As[2][32][72];   // 9216 B
  __shared__ short Ps[32][40];      // 2560 B
  __shared__ float S3[32][33];      // 4224 B
  __shared__ short Yt[4][64][40];   // 20480 B  -> total 36480 B / WG

  const int tid  = threadIdx.x;
  const int wv   = tid >> 6;        // wave id 0..3 -> owns cols [64*wv, 64*wv+64)
  const int lane = tid & 63;
  const int quad = lane >> 4;
  const int l16  = lane & 15;

  // ---- persistent W fragments in registers: wf[ks][td] holds
  // B[k = ks*32 + quad*8 + j][n = wv*64 + td*16 + l16]  (128 VGPRs) ----
  s16x8 wf[8][4];
  {
    const int ncol = wv * 64 + l16;
#pragma unroll
    for (int ks = 0; ks < 8; ++ks)
#pragma unroll
      for (int td = 0; td < 4; ++td) {
        const float* wp = w + (size_t)(ks * 32 + quad * 8) * DEPTH + ncol + td * 16;
#pragma unroll
        for (int j = 0; j < 8; ++j)
          wf[ks][td][j] = f2bf(wp[(size_t)j * DEPTH]);
      }
  }

  // s3 tile ownership: wave wv computes tile (tm_s, tn_s)
  const int tm_s = wv >> 1;
  const int tn_s = wv & 1;

  const int srow = tid >> 3;   // staging row 0..31
  const int sq   = tid & 7;    // 8 threads per row, 8 floats each

  for (int ib = 0; ib < ITERS; ++ib) {
    const int b = blockIdx.x + GRID * ib;

    f32x4 sacc = (f32x4){0.f, 0.f, 0.f, 0.f};
    f32x4 yacc[2][4];
#pragma unroll
    for (int i = 0; i < 2; ++i)
#pragma unroll
      for (int j = 0; j < 4; ++j) yacc[i][j] = (f32x4){0.f, 0.f, 0.f, 0.f};

    const float* xb = x + ((size_t)srow * BATCH + b) * DEPTH + sq * 8;

    // ---- stage chunk 0 (rows >= NJ zero-padded: kills NaN/Inf garbage) ----
    {
      float4 c0, c1;
      if (srow < NJ) {
        c0 = *(const float4*)(xb + 0);
        c1 = *(const float4*)(xb + 4);
      } else { c0 = make_float4(0.f, 0.f, 0.f, 0.f); c1 = c0; }
      s16x8 h;
      h[0]=f2bf(c0.x); h[1]=f2bf(c0.y); h[2]=f2bf(c0.z); h[3]=f2bf(c0.w);
      h[4]=f2bf(c1.x); h[5]=f2bf(c1.y); h[6]=f2bf(c1.z); h[7]=f2bf(c1.w);
      *(s16x8*)&As[0][srow][sq * 8] = h;
    }
    __syncthreads();

    // ---- K loop: 4 chunks of 64; each feeds s3 AND Y accumulation ----
#pragma unroll
    for (int kc = 0; kc < 4; ++kc) {
      float4 n0, n1;                     // prefetch next chunk (global, issued early)
      if (kc < 3) {
        if (srow < NJ) {
          n0 = *(const float4*)(xb + (kc + 1) * 64);
          n1 = *(const float4*)(xb + (kc + 1) * 64 + 4);
        } else { n0 = make_float4(0.f, 0.f, 0.f, 0.f); n1 = n0; }
      }
      const int buf = kc & 1;
#pragma unroll
      for (int s = 0; s < 2; ++s) {
        // A-operand frags: A[m = 16*tm + l16][k = 32*s + 8*quad + j]
        s16x8 a0 = *(const s16x8*)&As[buf][l16][s * 32 + quad * 8];
        s16x8 a1 = *(const s16x8*)&As[buf][16 + l16][s * 32 + quad * 8];
        // s3 tile for this wave (B-frag of A·A^T == A-frag of the tn rows)
        sacc = MFMA(tm_s ? a1 : a0, tn_s ? a1 : a0, sacc);
        const int ks = kc * 2 + s;
#pragma unroll
        for (int td = 0; td < 4; ++td) {
          yacc[0][td] = MFMA(a0, wf[ks][td], yacc[0][td]);
          yacc[1][td] = MFMA(a1, wf[ks][td], yacc[1][td]);
        }
      }
      if (kc < 3) {                      // write next chunk into the other buffer
        s16x8 h;
        h[0]=f2bf(n0.x); h[1]=f2bf(n0.y); h[2]=f2bf(n0.z); h[3]=f2bf(n0.w);
        h[4]=f2bf(n1.x); h[5]=f2bf(n1.y); h[6]=f2bf(n1.z); h[7]=f2bf(n1.w);
        *(s16x8*)&As[1 - buf][srow][sq * 8] = h;
      }
      __syncthreads();
    }

    // ---- epilogue: s3 -> LDS (C-layout: row = quad*4+r, col = l16) ----
#pragma unroll
    for (int r = 0; r < 4; ++r)
      S3[tm_s * 16 + quad * 4 + r][tn_s * 16 + l16] = sacc[r];
    __syncthreads();

    // softmax over m<25 (rows >=25 are zeros -> finite garbage, discarded at store)
    if (tid < 32) {
      const int row = tid;
      float mx = -3.0e38f;
      for (int j = 0; j < NJ; ++j) mx = fmaxf(mx, S3[row][j]);
      float sum = 0.f;
      for (int j = 0; j < NJ; ++j) sum += __expf(S3[row][j] - mx);
      const float rinv = 1.0f / sum;
      for (int j = 0; j < NJ; ++j) Ps[row][j] = f2bf(__expf(S3[row][j] - mx) * rinv);
      for (int j = NJ; j < 32; ++j) Ps[row][j] = 0;   // kill padded-K garbage in P@Y
    }
    __syncthreads();

    // ---- Y (C-layout accums) -> Yt[d][m] bf16, packed 4-m ds_write_b64 ----
#pragma unroll
    for (int tm = 0; tm < 2; ++tm)
#pragma unroll
      for (int td = 0; td < 4; ++td) {
        s16x4 hy;
#pragma unroll
        for (int r = 0; r < 4; ++r) hy[r] = f2bf(yacc[tm][td][r]);
        *(s16x4*)&Yt[wv][td * 16 + l16][tm * 16 + quad * 4] = hy;
      }
    // (same-wave DS ordering: writes precede reads in issue order, no barrier needed)

    // ---- out_strip = P @ Y_strip, store straight from C-layout ----
    s16x8 pf0 = *(const s16x8*)&Ps[l16][quad * 8];
    s16x8 pf1 = *(const s16x8*)&Ps[16 + l16][quad * 8];
    const f32x4 zero4 = (f32x4){0.f, 0.f, 0.f, 0.f};
    float* ob = out + (size_t)b * NJ * DEPTH + wv * 64 + l16;
#pragma unroll
    for (int td = 0; td < 4; ++td) {
      s16x8 yb = *(const s16x8*)&Yt[wv][td * 16 + l16][quad * 8];
      f32x4 o0 = MFMA(pf0, yb, zero4);
      f32x4 o1 = MFMA(pf1, yb, zero4);
#pragma unroll
      for (int r = 0; r < 4; ++r) {
        const int n0 = quad * 4 + r;                 // 0..15, always stored
        ob[(size_t)n0 * DEPTH + td * 16] = o0[r];
        const int n1 = 16 + quad * 4 + r;            // store only n < 25
        if (n1 < NJ) ob[(size_t)n1 * DEPTH + td * 16] = o1[r];
      }
    }
    // no trailing barrier needed: next iteration's first LDS write (As[0]) is
    // ordered behind its own pre-loop __syncthreads for every wave.
  }
}

extern "C" void kernel_launch(void* const* d_in, const int* in_sizes, int n_in,
                              void* d_out, int out_size, void* d_ws, size_t ws_size,
                              hipStream_t stream) {
  (void)in_sizes; (void)n_in; (void)out_size; (void)d_ws; (void)ws_size;
  const float* x = (const float*)d_in[0];
  const float* w = (const float*)d_in[1];
  float* out = (float*)d_out;
  geo_gcn_fused<<<dim3(GRID), dim3(BLOCK), 0, stream>>>(x, w, out);
}